// Round 18
// baseline (949.039 us; speedup 1.0000x reference)
//
#include <hip/hip_runtime.h>
#include <math.h>

#define N_NODES 100000
#define N_EDGES 3200000
#define F_NODE 4
#define F_EDGE 4
#define LD 6
#define HID 16
#define NLAYER 8
#define EPSF 1e-6f

#define NPB 64                      // nodes per bucket
#define NBK 1563                    // ceil(N_NODES/64)
#define NBIN 196                    // ceil(N_NODES/512): coarse bins of 512 nodes
#define G1 1000                     // blocks for hist/scatter
#define CH (N_EDGES / G1)           // 3200 edges per block
#define EPT ((CH + 255) / 256)      // 13 edges per thread in scatterA
#define SPLIT 4                     // hist sub-blocks per bin (edge-range quarters)
#define NSB (NBIN * SPLIT)          // 784
#define SPLITW 8                    // scatter sub-blocks per bin (one 64-node bucket each)
#define NSW (NBIN * SPLITW)         // 1568
#define SCAP2 3072                  // staging capacity per bucket (mean 2048 + 22 sigma)

// ---------- bf16 helpers (RNE pack, low half = first elem) ----------
__device__ __forceinline__ unsigned f2bf(float a, float b) {
    unsigned ua = __float_as_uint(a);
    ua = (ua + 0x7fffu + ((ua >> 16) & 1u)) >> 16;
    unsigned ub = __float_as_uint(b);
    ub = (ub + 0x7fffu + ((ub >> 16) & 1u)) & 0xffff0000u;
    return ua | ub;
}
__device__ __forceinline__ float bflo(unsigned u) { return __uint_as_float(u << 16); }
__device__ __forceinline__ float bfhi(unsigned u) { return __uint_as_float(u & 0xffff0000u); }

// ==================== phase 1: per-block LDS histograms over 196 coarse bins ====================
__global__ __launch_bounds__(256) void hist_kernel(const int* __restrict__ ei,
                                                   int* __restrict__ ghd,
                                                   int* __restrict__ ghs) {
    __shared__ int hd[NBIN];
    __shared__ int hs[NBIN];
    int t = threadIdx.x, blk = blockIdx.x;
    for (int i = t; i < NBIN; i += 256) { hd[i] = 0; hs[i] = 0; }
    __syncthreads();
    int beg = blk * CH, end = beg + CH;
    for (int e = beg + t; e < end; e += 256) {
        atomicAdd(&hs[ei[e] >> 9], 1);
        atomicAdd(&hd[ei[N_EDGES + e] >> 9], 1);
    }
    __syncthreads();
    for (int i = t; i < NBIN; i += 256) {
        ghd[(size_t)i * G1 + blk] = hd[i];
        ghs[(size_t)i * G1 + blk] = hs[i];
    }
}

// ==================== phase 2a: per-bin scan over blocks (bin-major, coalesced) ====================
__global__ __launch_bounds__(256) void scanb_kernel(int* __restrict__ ghd, int* __restrict__ ghs,
                                                    int* __restrict__ totd, int* __restrict__ tots) {
    __shared__ int part[256];
    int b = blockIdx.x, t = threadIdx.x;
#pragma unroll
    for (int a = 0; a < 2; a++) {
        int* g = a ? ghs : ghd;
        int vals[4];
        int sum = 0;
#pragma unroll
        for (int k = 0; k < 4; k++) {
            int idx = t * 4 + k;
            vals[k] = (idx < G1) ? g[(size_t)b * G1 + idx] : 0;
            sum += vals[k];
        }
        part[t] = sum;
        __syncthreads();
        for (int off = 1; off < 256; off <<= 1) {
            int v = (t >= off) ? part[t - off] : 0;
            __syncthreads();
            part[t] += v;
            __syncthreads();
        }
        int excl = part[t] - sum;
#pragma unroll
        for (int k = 0; k < 4; k++) {
            int idx = t * 4 + k;
            if (idx < G1) g[(size_t)b * G1 + idx] = excl;
            excl += vals[k];
        }
        if (t == 0) (a ? tots : totd)[b] = part[255];
        __syncthreads();
    }
}

// ==================== phase 2b: exclusive scan of bin totals ====================
__global__ __launch_bounds__(256) void totscan_kernel(const int* __restrict__ totd,
                                                      const int* __restrict__ tots,
                                                      int* __restrict__ binbased,
                                                      int* __restrict__ binbases) {
    __shared__ int part[256];
    int t = threadIdx.x;
#pragma unroll
    for (int a = 0; a < 2; a++) {
        const int* tot = a ? tots : totd;
        int* base = a ? binbases : binbased;
        int v = (t < NBIN) ? tot[t] : 0;
        part[t] = v;
        __syncthreads();
        for (int off = 1; off < 256; off <<= 1) {
            int u = (t >= off) ? part[t - off] : 0;
            __syncthreads();
            part[t] += u;
            __syncthreads();
        }
        if (t < NBIN) base[t] = part[t] - v;
        if (t == 0) base[NBIN] = N_EDGES;
        __syncthreads();
    }
}

// ==================== phase 3: scatter with block-local bin-sorted burst writes ====================
__global__ __launch_bounds__(256) void scatterA_kernel(const int* __restrict__ ei,
                                                       const float* __restrict__ ea,
                                                       const int* __restrict__ ghd,
                                                       const int* __restrict__ ghs,
                                                       const int* __restrict__ binbased,
                                                       const int* __restrict__ binbases,
                                                       unsigned* __restrict__ aw0,
                                                       unsigned* __restrict__ aw1,
                                                       unsigned* __restrict__ aw2,
                                                       unsigned* __restrict__ sbufA) {
    __shared__ int hcnt[NBIN];
    __shared__ int cdl[NBIN];
    __shared__ int gb[NBIN];
    __shared__ int part[256];
    __shared__ unsigned st0[CH];
    __shared__ unsigned st1[CH];
    __shared__ unsigned st2[CH];
    __shared__ unsigned stg[CH];
    int t = threadIdx.x, blk = blockIdx.x;
    int beg = blk * CH;
    int lidx[EPT];

    // ---------- pass D ----------
    for (int i = t; i < NBIN; i += 256) hcnt[i] = 0;
    __syncthreads();
    {
        int k = 0;
        for (int i = t; i < CH; i += 256, k++)
            lidx[k] = atomicAdd(&hcnt[ei[N_EDGES + beg + i] >> 9], 1);
    }
    __syncthreads();
    {
        int own = (t < NBIN) ? hcnt[t] : 0;
        part[t] = own;
        __syncthreads();
        for (int off = 1; off < 256; off <<= 1) {
            int v = (t >= off) ? part[t - off] : 0;
            __syncthreads();
            part[t] += v;
            __syncthreads();
        }
        if (t < NBIN) {
            cdl[t] = part[t] - own;
            gb[t] = binbased[t] + ghd[(size_t)t * G1 + blk];
        }
    }
    __syncthreads();
    {
        int k = 0;
        for (int i = t; i < CH; i += 256, k++) {
            int e = beg + i;
            int s = ei[e];
            int d = ei[N_EDGES + e];
            float4 ev = reinterpret_cast<const float4*>(ea)[e];
            int bin = d >> 9;
            int pos = cdl[bin] + lidx[k];
            st0[pos] = (unsigned)s | ((unsigned)(d & 511) << 17);
            st1[pos] = f2bf(ev.x, ev.y);
            st2[pos] = f2bf(ev.z, ev.w);
            stg[pos] = (unsigned)(gb[bin] + lidx[k]);
        }
    }
    __syncthreads();
    for (int i = t; i < CH; i += 256) {
        unsigned g = stg[i];
        aw0[g] = st0[i];
        aw1[g] = st1[i];
        aw2[g] = st2[i];
    }
    __syncthreads();

    // ---------- pass S ----------
    for (int i = t; i < NBIN; i += 256) hcnt[i] = 0;
    __syncthreads();
    {
        int k = 0;
        for (int i = t; i < CH; i += 256, k++)
            lidx[k] = atomicAdd(&hcnt[ei[beg + i] >> 9], 1);
    }
    __syncthreads();
    {
        int own = (t < NBIN) ? hcnt[t] : 0;
        part[t] = own;
        __syncthreads();
        for (int off = 1; off < 256; off <<= 1) {
            int v = (t >= off) ? part[t - off] : 0;
            __syncthreads();
            part[t] += v;
            __syncthreads();
        }
        if (t < NBIN) {
            cdl[t] = part[t] - own;
            gb[t] = binbases[t] + ghs[(size_t)t * G1 + blk];
        }
    }
    __syncthreads();
    {
        int k = 0;
        for (int i = t; i < CH; i += 256, k++) {
            int e = beg + i;
            int s = ei[e];
            int bin = s >> 9;
            int pos = cdl[bin] + lidx[k];
            st0[pos] = (unsigned)e | ((unsigned)(s & 511) << 22);
            stg[pos] = (unsigned)(gb[bin] + lidx[k]);
        }
    }
    __syncthreads();
    for (int i = t; i < CH; i += 256)
        sbufA[stg[i]] = st0[i];
}

// ==================== phase 4a: dst-sort histogram (edge-range quarters) ====================
__global__ __launch_bounds__(256) void sr_hist(const unsigned* __restrict__ aw0,
                                               const int* __restrict__ binbased,
                                               int* __restrict__ srh) {
    __shared__ int hist[512];
    int bs = blockIdx.x, t = threadIdx.x;
    int b = bs >> 2, h = bs & 3;
    hist[t] = 0; hist[t + 256] = 0;
    __syncthreads();
    int beg = binbased[b], end = binbased[b + 1];
    int len = end - beg;
    int p0 = beg + (int)((long long)len * h / SPLIT);
    int p1 = beg + (int)((long long)len * (h + 1) / SPLIT);
    for (int i = p0 + t; i < p1; i += 256)
        atomicAdd(&hist[(aw0[i] >> 17) & 511u], 1);
    __syncthreads();
    int* g = srh + (size_t)bs * 512;
    g[t] = hist[t];
    g[t + 256] = hist[t + 256];
}

// ==================== phase 4b: dst-sort scatter — per-BUCKET sub-blocks, LDS value staging ====================
__global__ __launch_bounds__(256) void sr_scat(const unsigned* __restrict__ aw0,
                                               const unsigned* __restrict__ aw1,
                                               const unsigned* __restrict__ aw2,
                                               const int* __restrict__ binbased,
                                               const int* __restrict__ srh,
                                               unsigned* __restrict__ bw0,
                                               unsigned* __restrict__ bw1,
                                               unsigned* __restrict__ bw2,
                                               float* __restrict__ degInv,
                                               int* __restrict__ based_bk) {
    __shared__ int cur[NPB];
    __shared__ int part[256];
    __shared__ int sSub[2];
    __shared__ unsigned stw0[SCAP2];
    __shared__ unsigned stw1[SCAP2];
    __shared__ unsigned stw2[SCAP2];
    int bs = blockIdx.x, t = threadIdx.x;
    int b = bs >> 3, h = bs & 7;
    int beg = binbased[b], end = binbased[b + 1];
    int j0 = 2 * t, j1 = 2 * t + 1;
    int tot0 = 0, tot1 = 0;
    const int* gbh = srh + (size_t)(b << 2) * 512;
#pragma unroll
    for (int hh = 0; hh < SPLIT; hh++) {
        tot0 += gbh[hh * 512 + j0];
        tot1 += gbh[hh * 512 + j1];
    }
    int tsum = tot0 + tot1;
    part[t] = tsum;
    __syncthreads();
    for (int off = 1; off < 256; off <<= 1) {
        int v = (t >= off) ? part[t - off] : 0;
        __syncthreads();
        part[t] += v;
        __syncthreads();
    }
    int excl = part[t] - tsum;
    int gcur0 = beg + excl;
    int gcur1 = gcur0 + tot0;
    int lo = h << 6, hi = lo + NPB;
    if (j0 == lo) sSub[0] = gcur0;
    if (h < 7) { if (j0 == hi) sSub[1] = gcur0; }
    else if (t == 0) sSub[1] = end;
    if (h == 0) {
        int node0 = b << 9;
        if (node0 + j0 < N_NODES) degInv[node0 + j0] = 1.0f / fmaxf((float)tot0, 1.0f);
        if (node0 + j1 < N_NODES) degInv[node0 + j1] = 1.0f / fmaxf((float)tot1, 1.0f);
        if ((j0 & 63) == 0) {
            int k = j0 >> 6;
            int node = node0 + (k << 6);
            if (node < N_NODES) based_bk[(b << 3) + k] = beg + excl;
        }
        if (b == NBIN - 1 && t == 0) based_bk[NBK] = N_EDGES;
    }
    __syncthreads();
    int subbase = sSub[0];
    if (j0 >= lo && j0 < hi) cur[j0 - lo] = gcur0 - subbase;
    if (j1 >= lo && j1 < hi) cur[j1 - lo] = gcur1 - subbase;
    __syncthreads();
    for (int i = beg + t; i < end; i += 256) {
        unsigned r0 = aw0[i];
        int nib = (int)((r0 >> 17) & 511u);
        if ((nib >> 6) == h) {
            unsigned v1 = aw1[i];
            unsigned v2 = aw2[i];
            int p = atomicAdd(&cur[nib & 63], 1);
            unsigned w = (r0 & 0x1FFFFu) | ((unsigned)(nib & 63) << 17);
            if (p < SCAP2) { stw0[p] = w; stw1[p] = v1; stw2[p] = v2; }
            else { bw0[subbase + p] = w; bw1[subbase + p] = v1; bw2[subbase + p] = v2; }
        }
    }
    __syncthreads();
    int tot = sSub[1] - subbase;
    if (tot > SCAP2) tot = SCAP2;
    for (int i = t; i < tot; i += 256) {
        bw0[subbase + i] = stw0[i];
        bw1[subbase + i] = stw1[i];
        bw2[subbase + i] = stw2[i];
    }
}

// ==================== phase 5a: src-sort histogram ====================
__global__ __launch_bounds__(256) void ss_hist(const unsigned* __restrict__ sbufA,
                                               const int* __restrict__ binbases,
                                               int* __restrict__ ssh) {
    __shared__ int hist[512];
    int bs = blockIdx.x, t = threadIdx.x;
    int b = bs >> 2, h = bs & 3;
    hist[t] = 0; hist[t + 256] = 0;
    __syncthreads();
    int beg = binbases[b], end = binbases[b + 1];
    int len = end - beg;
    int p0 = beg + (int)((long long)len * h / SPLIT);
    int p1 = beg + (int)((long long)len * (h + 1) / SPLIT);
    for (int i = p0 + t; i < p1; i += 256)
        atomicAdd(&hist[(sbufA[i] >> 22) & 511u], 1);
    __syncthreads();
    int* g = ssh + (size_t)bs * 512;
    g[t] = hist[t];
    g[t + 256] = hist[t + 256];
}

// ==================== phase 5b: src-sort scatter — per-BUCKET sub-blocks, LDS staging ====================
__global__ __launch_bounds__(256) void ss_scat(const unsigned* __restrict__ sbufA,
                                               const int* __restrict__ binbases,
                                               const int* __restrict__ ssh,
                                               unsigned* __restrict__ sbufB,
                                               int* __restrict__ bases_bk) {
    __shared__ int cur[NPB];
    __shared__ int part[256];
    __shared__ int sSub[2];
    __shared__ unsigned stw[SCAP2];
    int bs = blockIdx.x, t = threadIdx.x;
    int b = bs >> 3, h = bs & 7;
    int beg = binbases[b], end = binbases[b + 1];
    int j0 = 2 * t, j1 = 2 * t + 1;
    int tot0 = 0, tot1 = 0;
    const int* gbh = ssh + (size_t)(b << 2) * 512;
#pragma unroll
    for (int hh = 0; hh < SPLIT; hh++) {
        tot0 += gbh[hh * 512 + j0];
        tot1 += gbh[hh * 512 + j1];
    }
    int tsum = tot0 + tot1;
    part[t] = tsum;
    __syncthreads();
    for (int off = 1; off < 256; off <<= 1) {
        int v = (t >= off) ? part[t - off] : 0;
        __syncthreads();
        part[t] += v;
        __syncthreads();
    }
    int excl = part[t] - tsum;
    int gcur0 = beg + excl;
    int gcur1 = gcur0 + tot0;
    int lo = h << 6, hi = lo + NPB;
    if (j0 == lo) sSub[0] = gcur0;
    if (h < 7) { if (j0 == hi) sSub[1] = gcur0; }
    else if (t == 0) sSub[1] = end;
    if (h == 0) {
        if ((j0 & 63) == 0) {
            int k = j0 >> 6;
            int node = (b << 9) + (k << 6);
            if (node < N_NODES) bases_bk[(b << 3) + k] = beg + excl;
        }
        if (b == NBIN - 1 && t == 0) bases_bk[NBK] = N_EDGES;
    }
    __syncthreads();
    int subbase = sSub[0];
    if (j0 >= lo && j0 < hi) cur[j0 - lo] = gcur0 - subbase;
    if (j1 >= lo && j1 < hi) cur[j1 - lo] = gcur1 - subbase;
    __syncthreads();
    for (int i = beg + t; i < end; i += 256) {
        unsigned w = sbufA[i];
        int nib = (int)((w >> 22) & 511u);
        if ((nib >> 6) == h) {
            int p = atomicAdd(&cur[nib & 63], 1);
            unsigned wc = (w & 0x3FFFFFu) | ((unsigned)(nib & 63) << 22);
            if (p < SCAP2) stw[p] = wc;
            else sbufB[subbase + p] = wc;
        }
    }
    __syncthreads();
    int tot = sSub[1] - subbase;
    if (tot > SCAP2) tot = SCAP2;
    for (int i = t; i < tot; i += 256)
        sbufB[subbase + i] = stw[i];
}

// ==================== layer-0 A/B tables (X = 0) ====================
__global__ __launch_bounds__(256) void ab_init(const float* __restrict__ x,
                                               const float* __restrict__ W1,
                                               const float* __restrict__ b1,
                                               unsigned* __restrict__ A,
                                               unsigned* __restrict__ B) {
    __shared__ float sW[8 * HID];
    __shared__ float sb[HID];
    int t = threadIdx.x;
    for (int i = t; i < 8 * HID; i += 256) sW[i] = W1[12 * HID + i];
    if (t < HID) sb[t] = b1[t];
    __syncthreads();
    int i = blockIdx.x * 256 + t;
    if (i >= N_NODES) return;
    float4 xv = reinterpret_cast<const float4*>(x)[i];
    float xf[4] = {xv.x, xv.y, xv.z, xv.w};
    float a[HID], bb[HID];
#pragma unroll
    for (int j = 0; j < HID; j++) { a[j] = sb[j]; bb[j] = 0.0f; }
#pragma unroll
    for (int r = 0; r < 4; r++) {
        float v = xf[r];
#pragma unroll
        for (int j = 0; j < HID; j++) {
            a[j]  = fmaf(v, sW[r * HID + j], a[j]);
            bb[j] = fmaf(v, sW[(4 + r) * HID + j], bb[j]);
        }
    }
    uint4* Ao = reinterpret_cast<uint4*>(A + (size_t)i * 8);
    Ao[0] = make_uint4(f2bf(a[0], a[1]), f2bf(a[2], a[3]), f2bf(a[4], a[5]), f2bf(a[6], a[7]));
    Ao[1] = make_uint4(f2bf(a[8], a[9]), f2bf(a[10], a[11]), f2bf(a[12], a[13]), f2bf(a[14], a[15]));
    uint4* Bo = reinterpret_cast<uint4*>(B + (size_t)i * 8);
    Bo[0] = make_uint4(f2bf(bb[0], bb[1]), f2bf(bb[2], bb[3]), f2bf(bb[4], bb[5]), f2bf(bb[6], bb[7]));
    Bo[1] = make_uint4(f2bf(bb[8], bb[9]), f2bf(bb[10], bb[11]), f2bf(bb[12], bb[13]), f2bf(bb[14], bb[15]));
}

// ==================== node projection: X,x -> next-layer A/B tables ====================
__global__ __launch_bounds__(256) void node_proj(const float* __restrict__ X,
                                                 const float* __restrict__ x,
                                                 const float* __restrict__ W1n,
                                                 const float* __restrict__ b1n,
                                                 unsigned* __restrict__ A,
                                                 unsigned* __restrict__ B) {
    __shared__ float sW[20 * HID];
    __shared__ float sb[HID];
    int t = threadIdx.x;
    for (int i = t; i < 20 * HID; i += 256) sW[i] = W1n[i];
    if (t < HID) sb[t] = b1n[t];
    __syncthreads();
    int i = blockIdx.x * 256 + t;
    if (i >= N_NODES) return;
    const float4* Xp = reinterpret_cast<const float4*>(X + (size_t)i * 8);
    float4 x0 = Xp[0], x1 = Xp[1];
    float Xv[LD] = {x0.x, x0.y, x0.z, x0.w, x1.x, x1.y};
    float4 xv = reinterpret_cast<const float4*>(x)[i];
    float xf[4] = {xv.x, xv.y, xv.z, xv.w};
    float a[HID], bb[HID];
#pragma unroll
    for (int j = 0; j < HID; j++) { a[j] = sb[j]; bb[j] = 0.0f; }
#pragma unroll
    for (int rr = 0; rr < LD; rr++) {
        float v = Xv[rr];
#pragma unroll
        for (int j = 0; j < HID; j++) {
            a[j]  = fmaf(v, sW[rr * HID + j], a[j]);
            bb[j] = fmaf(v, sW[(LD + rr) * HID + j], bb[j]);
        }
    }
#pragma unroll
    for (int rr = 0; rr < 4; rr++) {
        float v = xf[rr];
#pragma unroll
        for (int j = 0; j < HID; j++) {
            a[j]  = fmaf(v, sW[(12 + rr) * HID + j], a[j]);
            bb[j] = fmaf(v, sW[(16 + rr) * HID + j], bb[j]);
        }
    }
    uint4* Ao = reinterpret_cast<uint4*>(A + (size_t)i * 8);
    Ao[0] = make_uint4(f2bf(a[0], a[1]), f2bf(a[2], a[3]), f2bf(a[4], a[5]), f2bf(a[6], a[7]));
    Ao[1] = make_uint4(f2bf(a[8], a[9]), f2bf(a[10], a[11]), f2bf(a[12], a[13]), f2bf(a[14], a[15]));
    uint4* Bo = reinterpret_cast<uint4*>(B + (size_t)i * 8);
    Bo[0] = make_uint4(f2bf(bb[0], bb[1]), f2bf(bb[2], bb[3]), f2bf(bb[4], bb[5]), f2bf(bb[6], bb[7]));
    Bo[1] = make_uint4(f2bf(bb[8], bb[9]), f2bf(bb[10], bb[11]), f2bf(bb[12], bb[13]), f2bf(bb[14], bb[15]));
}

// ==================== per-layer edge kernel: 4 edges/thread, hoisted A prefetch ====================
template <int LAST>
__global__ __launch_bounds__(512) void edge_layer(const unsigned* __restrict__ bw0,
                                                  const unsigned* __restrict__ bw1,
                                                  const unsigned* __restrict__ bw2,
                                                  const unsigned* __restrict__ Ain,
                                                  const unsigned* __restrict__ Bin,
                                                  const float* __restrict__ x,
                                                  const float* __restrict__ degInv,
                                                  const float* __restrict__ W1l,
                                                  const float* __restrict__ W2l,
                                                  const float* __restrict__ b2l,
                                                  const float* __restrict__ Wf,
                                                  const float* __restrict__ bfp,
                                                  const int* __restrict__ based_bk,
                                                  float* __restrict__ Xout,
                                                  float* __restrict__ Pout,
                                                  float* __restrict__ Pbuf) {
    __shared__ float sWea[4 * HID];
    __shared__ float sW2[HID * LD];
    __shared__ float sb2[LD];
    __shared__ float sWf[LD];
    __shared__ float sbf;
    __shared__ float accf[NPB * 8];     // [key*8 + o]
    __shared__ unsigned sB[NPB * 8];
    int t = threadIdx.x;
    int b = blockIdx.x;
    for (int i = t; i < 4 * HID; i += 512) sWea[i] = W1l[20 * HID + i];
    for (int i = t; i < HID * LD; i += 512) sW2[i] = W2l[i];
    if (t < LD) sb2[t] = b2l[t];
    if (LAST) {
        if (t < LD) sWf[t] = Wf[t];
        if (t == 0) sbf = bfp[0];
    }
    if (t < NPB * 8) accf[t] = 0.0f;
    {
        size_t base8 = (size_t)(b << 6) * 8;
        for (int i = t; i < NPB * 8; i += 512) {
            size_t gi = base8 + i;
            sB[i] = (gi < (size_t)N_NODES * 8) ? Bin[gi] : 0u;
        }
    }
    __syncthreads();

    int beg = based_bk[b], end = based_bk[b + 1];
    int abeg = beg & ~3;
    int nQuads = (end - abeg + 3) >> 2;
    int lane = t & 63;

    float out[LD];
    auto edge_compute = [&](uint4 ax, uint4 ay, unsigned w1w, unsigned w2w, int key) {
        const uint4* Bp = reinterpret_cast<const uint4*>(sB) + (key << 1);
        uint4 bx = Bp[0], by = Bp[1];
        float h[HID];
        h[0]  = bflo(ax.x) + bflo(bx.x);  h[1]  = bfhi(ax.x) + bfhi(bx.x);
        h[2]  = bflo(ax.y) + bflo(bx.y);  h[3]  = bfhi(ax.y) + bfhi(bx.y);
        h[4]  = bflo(ax.z) + bflo(bx.z);  h[5]  = bfhi(ax.z) + bfhi(bx.z);
        h[6]  = bflo(ax.w) + bflo(bx.w);  h[7]  = bfhi(ax.w) + bfhi(bx.w);
        h[8]  = bflo(ay.x) + bflo(by.x);  h[9]  = bfhi(ay.x) + bfhi(by.x);
        h[10] = bflo(ay.y) + bflo(by.y);  h[11] = bfhi(ay.y) + bfhi(by.y);
        h[12] = bflo(ay.z) + bflo(by.z);  h[13] = bfhi(ay.z) + bfhi(by.z);
        h[14] = bflo(ay.w) + bflo(by.w);  h[15] = bfhi(ay.w) + bfhi(by.w);
        float ef[4] = {bflo(w1w), bfhi(w1w), bflo(w2w), bfhi(w2w)};
#pragma unroll
        for (int rr = 0; rr < 4; rr++) {
            float v = ef[rr];
#pragma unroll
            for (int j = 0; j < HID; j++) h[j] = fmaf(v, sWea[rr * HID + j], h[j]);
        }
#pragma unroll
        for (int j = 0; j < HID; j++) h[j] = fmaxf(h[j], 0.0f);
        float mo[LD];
#pragma unroll
        for (int o = 0; o < LD; o++) mo[o] = sb2[o];
#pragma unroll
        for (int j = 0; j < HID; j++) {
            float hj = h[j];
#pragma unroll
            for (int o = 0; o < LD; o++) mo[o] = fmaf(hj, sW2[j * LD + o], mo[o]);
        }
#pragma unroll
        for (int o = 0; o < LD; o++) out[o] += mo[o];
    };

    for (int qb = 0; qb < nQuads; qb += 512) {
        int c = qb + t;
        int key = -1;
#pragma unroll
        for (int o = 0; o < LD; o++) out[o] = 0.0f;

        if (c < nQuads) {
            int p0 = abeg + (c << 2);
            uint4 r0 = *reinterpret_cast<const uint4*>(bw0 + p0);
            uint4 w1 = *reinterpret_cast<const uint4*>(bw1 + p0);
            uint4 w2 = *reinterpret_cast<const uint4*>(bw2 + p0);
            unsigned r0a[4] = {r0.x, r0.y, r0.z, r0.w};
            unsigned w1a[4] = {w1.x, w1.y, w1.z, w1.w};
            unsigned w2a[4] = {w2.x, w2.y, w2.z, w2.w};
            bool va[4];
            uint4 axr[4], ayr[4];
#pragma unroll
            for (int j = 0; j < 4; j++) {
                int p = p0 + j;
                va[j] = (p >= beg) && (p < end);
                if (va[j]) {
                    const uint4* Ap = reinterpret_cast<const uint4*>(Ain + (size_t)(r0a[j] & 0x1FFFFu) * 8);
                    axr[j] = Ap[0];
                    ayr[j] = Ap[1];
                }
            }
#pragma unroll
            for (int j = 0; j < 4; j++) {
                if (!va[j]) continue;
                int kj = (int)((r0a[j] >> 17) & 63u);
                if (kj != key) {
                    if (key >= 0) {
#pragma unroll
                        for (int o = 0; o < LD; o++) atomicAdd(&accf[(key << 3) + o], out[o]);
#pragma unroll
                        for (int o = 0; o < LD; o++) out[o] = 0.0f;
                    }
                    key = kj;
                }
                edge_compute(axr[j], ayr[j], w1a[j], w2a[j], key);
            }
        }

        // wave segmented inclusive sum over per-thread partials (keys sorted)
#pragma unroll
        for (int st = 1; st < 64; st <<= 1) {
            int kup = __shfl_up(key, st, 64);
            bool same = (lane >= st) && (kup == key);
#pragma unroll
            for (int o = 0; o < LD; o++) {
                float v = __shfl_up(out[o], st, 64);
                if (same) out[o] += v;
            }
        }
        int knx = __shfl_down(key, 1, 64);
        bool tail = (lane == 63) || (knx != key);
        if (tail && key >= 0) {
#pragma unroll
            for (int o = 0; o < LD; o++) atomicAdd(&accf[(key << 3) + o], out[o]);
        }
    }
    __syncthreads();

    if (t < NPB) {
        int gid = (b << 6) + t;
        if (gid < N_NODES) {
            float inv = degInv[gid];
            float Xv[LD];
#pragma unroll
            for (int o = 0; o < LD; o++) Xv[o] = fmaxf(accf[(t << 3) + o] * inv, 0.0f);
            if (LAST) {
                float a2 = sbf;
#pragma unroll
                for (int o = 0; o < LD; o++) a2 = fmaf(Xv[o], sWf[o], a2);
                float P = fmaxf(a2, 0.0f);
                Pout[gid] = P;
                float fx = x[gid * F_NODE + 3];
                Pbuf[gid] = (fx != 0.0f) ? fx : P;
            } else {
                float4* Xp = reinterpret_cast<float4*>(Xout + (size_t)gid * 8);
                Xp[0] = make_float4(Xv[0], Xv[1], Xv[2], Xv[3]);
                Xp[1] = make_float4(Xv[4], Xv[5], 0.0f, 0.0f);
            }
        }
    }
}

// ==================== flows (original order, exact fp32) ====================
__global__ __launch_bounds__(256) void flows_noatomic(const int* __restrict__ ei,
                                                      const float* __restrict__ ea,
                                                      const float* __restrict__ Pbuf,
                                                      float* __restrict__ flows_out) {
    int e = blockIdx.x * 256 + threadIdx.x;
    if (e >= N_EDGES) return;
    int s = ei[e];
    int d = ei[N_EDGES + e];
    float ps = Pbuf[s], pd = Pbuf[d];
    float dp2 = ps * ps - pd * pd;
    float k = ea[(size_t)e * F_EDGE];
    float sg = (dp2 > 0.0f) ? 1.0f : ((dp2 < 0.0f) ? -1.0f : 0.0f);
    flows_out[e] = sg * sqrtf(fabsf(dp2) / k + EPSF);
}

// ==================== balance in-flow: recompute flows from sorted planes, segscan ====================
__global__ __launch_bounds__(256) void balance_in(const unsigned* __restrict__ bw0,
                                                  const unsigned* __restrict__ bw1,
                                                  const float* __restrict__ Pbuf,
                                                  const float* __restrict__ x,
                                                  const int* __restrict__ based_bk,
                                                  float* __restrict__ bal) {
    __shared__ float acc[NPB];
    __shared__ float pdl[NPB];
    int t = threadIdx.x;
    int b = blockIdx.x;
    if (t < NPB) {
        acc[t] = 0.0f;
        int gid = (b << 6) + t;
        pdl[t] = (gid < N_NODES) ? Pbuf[gid] : 0.0f;
    }
    __syncthreads();
    int beg = based_bk[b], end = based_bk[b + 1];
    int lane = t & 63;
    for (int base = beg; base < end; base += 256) {
        int p = base + t;
        bool valid = p < end;
        int key = -1;
        float f = 0.0f;
        if (valid) {
            unsigned r0 = bw0[p];
            int s = (int)(r0 & 0x1FFFFu);
            key = (int)((r0 >> 17) & 63u);
            float ps = Pbuf[s];
            float pd = pdl[key];
            float k = bflo(bw1[p]);
            float dp2 = ps * ps - pd * pd;
            float sg = (dp2 > 0.0f) ? 1.0f : ((dp2 < 0.0f) ? -1.0f : 0.0f);
            f = sg * sqrtf(fabsf(dp2) / k + EPSF);
        }
#pragma unroll
        for (int st = 1; st < 64; st <<= 1) {
            int kup = __shfl_up(key, st, 64);
            float v = __shfl_up(f, st, 64);
            if ((lane >= st) && (kup == key)) f += v;
        }
        int knx = __shfl_down(key, 1, 64);
        bool tail = (lane == 63) || (knx != key);
        if (valid && tail) atomicAdd(&acc[key], f);
    }
    __syncthreads();
    if (t < NPB) {
        int gid = (b << 6) + t;
        if (gid < N_NODES) bal[gid] = acc[t] + x[gid * F_NODE + 0];
    }
}

// ==================== balance out-flow (segscan over sorted sbufB) + imbalance ====================
__global__ __launch_bounds__(256) void balance_out(const unsigned* __restrict__ sbufB,
                                                   const float* __restrict__ flows,
                                                   const int* __restrict__ bases_bk,
                                                   const float* __restrict__ bal,
                                                   float* __restrict__ imb2) {
    __shared__ float acc[NPB];
    int t = threadIdx.x;
    if (t < NPB) acc[t] = 0.0f;
    __syncthreads();
    int b = blockIdx.x;
    int beg = bases_bk[b], end = bases_bk[b + 1];
    int lane = t & 63;
    for (int base = beg; base < end; base += 256) {
        int q = base + t;
        bool valid = q < end;
        int key = -1;
        float f = 0.0f;
        if (valid) {
            unsigned u = sbufB[q];
            key = (int)((u >> 22) & 63u);
            f = flows[u & 0x3FFFFFu];
        }
#pragma unroll
        for (int st = 1; st < 64; st <<= 1) {
            int kup = __shfl_up(key, st, 64);
            float v = __shfl_up(f, st, 64);
            if ((lane >= st) && (kup == key)) f += v;
        }
        int knx = __shfl_down(key, 1, 64);
        bool tail = (lane == 63) || (knx != key);
        if (valid && tail) atomicAdd(&acc[key], f);
    }
    __syncthreads();
    if (t < NPB) {
        float v = 0.0f;
        int gid = (b << 6) + t;
        if (gid < N_NODES) {
            float bv = bal[gid] - acc[t];
            v = bv * bv;
        }
#pragma unroll
        for (int off = 32; off > 0; off >>= 1) v += __shfl_down(v, off, 64);
        if (t == 0) atomicAdd(imb2, v);
    }
}

__global__ void fin_kernel(const float* __restrict__ imb2, float* __restrict__ out) {
    out[0] = sqrtf(imb2[0]);
}

// ==================== launch ====================
extern "C" void kernel_launch(void* const* d_in, const int* in_sizes, int n_in,
                              void* d_out, int out_size, void* d_ws, size_t ws_size,
                              hipStream_t stream) {
    const float* x   = (const float*)d_in[0];
    const float* ea  = (const float*)d_in[1];
    const int*   ei  = (const int*)d_in[2];
    const float* W1  = (const float*)d_in[3];
    const float* b1  = (const float*)d_in[4];
    const float* W2  = (const float*)d_in[5];
    const float* b2  = (const float*)d_in[6];
    const float* Wf  = (const float*)d_in[7];
    const float* bf_ = (const float*)d_in[8];
    float* out = (float*)d_out;

    const size_t N = N_NODES, E = N_EDGES;

    // ---- workspace layout (4B elements), ~110 MB ----
    size_t o = 0;
    auto alloc = [&](size_t n) { size_t r = o; o += (n + 3) & ~(size_t)3; return r; };
    size_t o_bw0      = alloc(E);
    size_t o_bw1      = alloc(E);
    size_t o_bw2      = alloc(E);
    size_t o_aw0      = alloc(E);      // sbufB overlays aw0 after sr_scat
    size_t o_aw1      = alloc(E);
    size_t o_aw2      = alloc(E);
    size_t o_sbufA    = alloc(E);
    size_t o_ghd      = alloc((size_t)NBIN * G1);
    size_t o_ghs      = alloc((size_t)NBIN * G1);
    size_t o_srh      = alloc((size_t)NSB * 512);
    size_t o_ssh      = alloc((size_t)NSB * 512);
    size_t o_totd     = alloc(NBIN);
    size_t o_tots     = alloc(NBIN);
    size_t o_binbased = alloc(NBIN + 1);
    size_t o_binbases = alloc(NBIN + 1);
    size_t o_basedbk  = alloc(NBK + 1);
    size_t o_basesbk  = alloc(NBK + 1);
    size_t o_degInv   = alloc(N);
    size_t o_A0       = alloc(8 * N);
    size_t o_B0       = alloc(8 * N);
    size_t o_A1       = alloc(8 * N);
    size_t o_B1       = alloc(8 * N);
    size_t o_X        = alloc(8 * N);
    size_t o_Pbuf     = alloc(N);
    size_t o_bal      = alloc(N);
    size_t o_imb2     = alloc(16);
    (void)o;

    int* wsi = (int*)d_ws;
    unsigned* bw0      = (unsigned*)(wsi + o_bw0);
    unsigned* bw1      = (unsigned*)(wsi + o_bw1);
    unsigned* bw2      = (unsigned*)(wsi + o_bw2);
    unsigned* aw0      = (unsigned*)(wsi + o_aw0);
    unsigned* aw1      = (unsigned*)(wsi + o_aw1);
    unsigned* aw2      = (unsigned*)(wsi + o_aw2);
    unsigned* sbufA    = (unsigned*)(wsi + o_sbufA);
    unsigned* sbufB    = (unsigned*)(wsi + o_aw0);   // overlay (aw* dead after sr_scat)
    int*      ghd      = wsi + o_ghd;
    int*      ghs      = wsi + o_ghs;
    int*      srh      = wsi + o_srh;
    int*      ssh      = wsi + o_ssh;
    int*      totd     = wsi + o_totd;
    int*      tots     = wsi + o_tots;
    int*      binbased = wsi + o_binbased;
    int*      binbases = wsi + o_binbases;
    int*      based_bk = wsi + o_basedbk;
    int*      bases_bk = wsi + o_basesbk;
    float*    degInv   = (float*)(wsi + o_degInv);
    unsigned* A0       = (unsigned*)(wsi + o_A0);
    unsigned* B0       = (unsigned*)(wsi + o_B0);
    unsigned* A1       = (unsigned*)(wsi + o_A1);
    unsigned* B1       = (unsigned*)(wsi + o_B1);
    float*    Xbuf     = (float*)(wsi + o_X);
    float*    Pbuf     = (float*)(wsi + o_Pbuf);
    float*    bal      = (float*)(wsi + o_bal);
    float*    imb2     = (float*)(wsi + o_imb2);

    const int NB = (N_NODES + 255) / 256;   // 391
    const int EB = (N_EDGES + 255) / 256;   // 12500

    hipMemsetAsync(imb2, 0, sizeof(float), stream);

    hist_kernel<<<G1, 256, 0, stream>>>(ei, ghd, ghs);
    scanb_kernel<<<NBIN, 256, 0, stream>>>(ghd, ghs, totd, tots);
    totscan_kernel<<<1, 256, 0, stream>>>(totd, tots, binbased, binbases);
    scatterA_kernel<<<G1, 256, 0, stream>>>(ei, ea, ghd, ghs, binbased, binbases,
                                            aw0, aw1, aw2, sbufA);
    sr_hist<<<NSB, 256, 0, stream>>>(aw0, binbased, srh);
    sr_scat<<<NSW, 256, 0, stream>>>(aw0, aw1, aw2, binbased, srh,
                                     bw0, bw1, bw2, degInv, based_bk);
    ss_hist<<<NSB, 256, 0, stream>>>(sbufA, binbases, ssh);
    ss_scat<<<NSW, 256, 0, stream>>>(sbufA, binbases, ssh, sbufB, bases_bk);

    ab_init<<<NB, 256, 0, stream>>>(x, W1, b1, A0, B0);

    for (int l = 0; l < NLAYER; l++) {
        const unsigned* Ain = (l & 1) ? A1 : A0;
        const unsigned* Bin = (l & 1) ? B1 : B0;
        unsigned* Aout = (l & 1) ? A0 : A1;
        unsigned* Bout = (l & 1) ? B0 : B1;
        const float* W1l = W1 + (size_t)l * 24 * HID;
        const float* W2l = W2 + (size_t)l * HID * LD;
        const float* b2l = b2 + (size_t)l * LD;
        if (l < NLAYER - 1) {
            edge_layer<0><<<NBK, 512, 0, stream>>>(bw0, bw1, bw2, Ain, Bin, x, degInv,
                                                   W1l, W2l, b2l, Wf, bf_, based_bk,
                                                   Xbuf, out, Pbuf);
            node_proj<<<NB, 256, 0, stream>>>(Xbuf, x,
                                              W1 + (size_t)(l + 1) * 24 * HID,
                                              b1 + (size_t)(l + 1) * HID,
                                              Aout, Bout);
        } else {
            edge_layer<1><<<NBK, 512, 0, stream>>>(bw0, bw1, bw2, Ain, Bin, x, degInv,
                                                   W1l, W2l, b2l, Wf, bf_, based_bk,
                                                   Xbuf, out, Pbuf);
        }
    }

    flows_noatomic<<<EB, 256, 0, stream>>>(ei, ea, Pbuf, out + N);
    balance_in<<<NBK, 256, 0, stream>>>(bw0, bw1, Pbuf, x, based_bk, bal);
    balance_out<<<NBK, 256, 0, stream>>>(sbufB, out + N, bases_bk, bal, imb2);
    fin_kernel<<<1, 1, 0, stream>>>(imb2, out + (size_t)N + E);
}

// Round 19
// 854.069 us; speedup vs baseline: 1.1112x; 1.1112x over previous
//
#include <hip/hip_runtime.h>
#include <math.h>

#define N_NODES 100000
#define N_EDGES 3200000
#define F_NODE 4
#define F_EDGE 4
#define LD 6
#define HID 16
#define NLAYER 8
#define EPSF 1e-6f

#define NPB 64                      // nodes per bucket
#define NBK 1563                    // ceil(N_NODES/64)
#define NBIN 196                    // ceil(N_NODES/512): coarse bins of 512 nodes
#define G1 1000                     // blocks for hist/scatter
#define CH (N_EDGES / G1)           // 3200 edges per block
#define EPT ((CH + 255) / 256)      // 13 edges per thread in scatterA
#define SPLIT 4                     // hist sub-blocks per bin (edge-range quarters)
#define NSB (NBIN * SPLIT)          // 784
#define SPLITW 8                    // scatter sub-blocks per bin (one 64-node bucket each)
#define NSW (NBIN * SPLITW)         // 1568
#define SCAP2 3072                  // staging capacity per bucket (mean 2048 + 22 sigma)

// ---------- bf16 helpers (RNE pack, low half = first elem) ----------
__device__ __forceinline__ unsigned f2bf(float a, float b) {
    unsigned ua = __float_as_uint(a);
    ua = (ua + 0x7fffu + ((ua >> 16) & 1u)) >> 16;
    unsigned ub = __float_as_uint(b);
    ub = (ub + 0x7fffu + ((ub >> 16) & 1u)) & 0xffff0000u;
    return ua | ub;
}
__device__ __forceinline__ float bflo(unsigned u) { return __uint_as_float(u << 16); }
__device__ __forceinline__ float bfhi(unsigned u) { return __uint_as_float(u & 0xffff0000u); }

// ==================== phase 1: per-block LDS histograms over 196 coarse bins ====================
__global__ __launch_bounds__(256) void hist_kernel(const int* __restrict__ ei,
                                                   int* __restrict__ ghd,
                                                   int* __restrict__ ghs) {
    __shared__ int hd[NBIN];
    __shared__ int hs[NBIN];
    int t = threadIdx.x, blk = blockIdx.x;
    for (int i = t; i < NBIN; i += 256) { hd[i] = 0; hs[i] = 0; }
    __syncthreads();
    int beg = blk * CH, end = beg + CH;
    for (int e = beg + t; e < end; e += 256) {
        atomicAdd(&hs[ei[e] >> 9], 1);
        atomicAdd(&hd[ei[N_EDGES + e] >> 9], 1);
    }
    __syncthreads();
    for (int i = t; i < NBIN; i += 256) {
        ghd[(size_t)i * G1 + blk] = hd[i];
        ghs[(size_t)i * G1 + blk] = hs[i];
    }
}

// ==================== phase 2a: per-bin scan over blocks (bin-major, coalesced) ====================
__global__ __launch_bounds__(256) void scanb_kernel(int* __restrict__ ghd, int* __restrict__ ghs,
                                                    int* __restrict__ totd, int* __restrict__ tots) {
    __shared__ int part[256];
    int b = blockIdx.x, t = threadIdx.x;
#pragma unroll
    for (int a = 0; a < 2; a++) {
        int* g = a ? ghs : ghd;
        int vals[4];
        int sum = 0;
#pragma unroll
        for (int k = 0; k < 4; k++) {
            int idx = t * 4 + k;
            vals[k] = (idx < G1) ? g[(size_t)b * G1 + idx] : 0;
            sum += vals[k];
        }
        part[t] = sum;
        __syncthreads();
        for (int off = 1; off < 256; off <<= 1) {
            int v = (t >= off) ? part[t - off] : 0;
            __syncthreads();
            part[t] += v;
            __syncthreads();
        }
        int excl = part[t] - sum;
#pragma unroll
        for (int k = 0; k < 4; k++) {
            int idx = t * 4 + k;
            if (idx < G1) g[(size_t)b * G1 + idx] = excl;
            excl += vals[k];
        }
        if (t == 0) (a ? tots : totd)[b] = part[255];
        __syncthreads();
    }
}

// ==================== phase 2b: exclusive scan of bin totals ====================
__global__ __launch_bounds__(256) void totscan_kernel(const int* __restrict__ totd,
                                                      const int* __restrict__ tots,
                                                      int* __restrict__ binbased,
                                                      int* __restrict__ binbases) {
    __shared__ int part[256];
    int t = threadIdx.x;
#pragma unroll
    for (int a = 0; a < 2; a++) {
        const int* tot = a ? tots : totd;
        int* base = a ? binbases : binbased;
        int v = (t < NBIN) ? tot[t] : 0;
        part[t] = v;
        __syncthreads();
        for (int off = 1; off < 256; off <<= 1) {
            int u = (t >= off) ? part[t - off] : 0;
            __syncthreads();
            part[t] += u;
            __syncthreads();
        }
        if (t < NBIN) base[t] = part[t] - v;
        if (t == 0) base[NBIN] = N_EDGES;
        __syncthreads();
    }
}

// ==================== phase 3: scatter with block-local bin-sorted burst writes ====================
__global__ __launch_bounds__(256) void scatterA_kernel(const int* __restrict__ ei,
                                                       const float* __restrict__ ea,
                                                       const int* __restrict__ ghd,
                                                       const int* __restrict__ ghs,
                                                       const int* __restrict__ binbased,
                                                       const int* __restrict__ binbases,
                                                       unsigned* __restrict__ aw0,
                                                       unsigned* __restrict__ aw1,
                                                       unsigned* __restrict__ aw2,
                                                       unsigned* __restrict__ sbufA) {
    __shared__ int hcnt[NBIN];
    __shared__ int cdl[NBIN];
    __shared__ int gb[NBIN];
    __shared__ int part[256];
    __shared__ unsigned st0[CH];
    __shared__ unsigned st1[CH];
    __shared__ unsigned st2[CH];
    __shared__ unsigned stg[CH];
    int t = threadIdx.x, blk = blockIdx.x;
    int beg = blk * CH;
    int lidx[EPT];

    // ---------- pass D ----------
    for (int i = t; i < NBIN; i += 256) hcnt[i] = 0;
    __syncthreads();
    {
        int k = 0;
        for (int i = t; i < CH; i += 256, k++)
            lidx[k] = atomicAdd(&hcnt[ei[N_EDGES + beg + i] >> 9], 1);
    }
    __syncthreads();
    {
        int own = (t < NBIN) ? hcnt[t] : 0;
        part[t] = own;
        __syncthreads();
        for (int off = 1; off < 256; off <<= 1) {
            int v = (t >= off) ? part[t - off] : 0;
            __syncthreads();
            part[t] += v;
            __syncthreads();
        }
        if (t < NBIN) {
            cdl[t] = part[t] - own;
            gb[t] = binbased[t] + ghd[(size_t)t * G1 + blk];
        }
    }
    __syncthreads();
    {
        int k = 0;
        for (int i = t; i < CH; i += 256, k++) {
            int e = beg + i;
            int s = ei[e];
            int d = ei[N_EDGES + e];
            float4 ev = reinterpret_cast<const float4*>(ea)[e];
            int bin = d >> 9;
            int pos = cdl[bin] + lidx[k];
            st0[pos] = (unsigned)s | ((unsigned)(d & 511) << 17);
            st1[pos] = f2bf(ev.x, ev.y);
            st2[pos] = f2bf(ev.z, ev.w);
            stg[pos] = (unsigned)(gb[bin] + lidx[k]);
        }
    }
    __syncthreads();
    for (int i = t; i < CH; i += 256) {
        unsigned g = stg[i];
        aw0[g] = st0[i];
        aw1[g] = st1[i];
        aw2[g] = st2[i];
    }
    __syncthreads();

    // ---------- pass S ----------
    for (int i = t; i < NBIN; i += 256) hcnt[i] = 0;
    __syncthreads();
    {
        int k = 0;
        for (int i = t; i < CH; i += 256, k++)
            lidx[k] = atomicAdd(&hcnt[ei[beg + i] >> 9], 1);
    }
    __syncthreads();
    {
        int own = (t < NBIN) ? hcnt[t] : 0;
        part[t] = own;
        __syncthreads();
        for (int off = 1; off < 256; off <<= 1) {
            int v = (t >= off) ? part[t - off] : 0;
            __syncthreads();
            part[t] += v;
            __syncthreads();
        }
        if (t < NBIN) {
            cdl[t] = part[t] - own;
            gb[t] = binbases[t] + ghs[(size_t)t * G1 + blk];
        }
    }
    __syncthreads();
    {
        int k = 0;
        for (int i = t; i < CH; i += 256, k++) {
            int e = beg + i;
            int s = ei[e];
            int bin = s >> 9;
            int pos = cdl[bin] + lidx[k];
            st0[pos] = (unsigned)e | ((unsigned)(s & 511) << 22);
            stg[pos] = (unsigned)(gb[bin] + lidx[k]);
        }
    }
    __syncthreads();
    for (int i = t; i < CH; i += 256)
        sbufA[stg[i]] = st0[i];
}

// ==================== phase 4a: dst-sort histogram (edge-range quarters) ====================
__global__ __launch_bounds__(256) void sr_hist(const unsigned* __restrict__ aw0,
                                               const int* __restrict__ binbased,
                                               int* __restrict__ srh) {
    __shared__ int hist[512];
    int bs = blockIdx.x, t = threadIdx.x;
    int b = bs >> 2, h = bs & 3;
    hist[t] = 0; hist[t + 256] = 0;
    __syncthreads();
    int beg = binbased[b], end = binbased[b + 1];
    int len = end - beg;
    int p0 = beg + (int)((long long)len * h / SPLIT);
    int p1 = beg + (int)((long long)len * (h + 1) / SPLIT);
    for (int i = p0 + t; i < p1; i += 256)
        atomicAdd(&hist[(aw0[i] >> 17) & 511u], 1);
    __syncthreads();
    int* g = srh + (size_t)bs * 512;
    g[t] = hist[t];
    g[t + 256] = hist[t + 256];
}

// ==================== phase 4b: dst-sort scatter — per-BUCKET sub-blocks, LDS value staging ====================
__global__ __launch_bounds__(256) void sr_scat(const unsigned* __restrict__ aw0,
                                               const unsigned* __restrict__ aw1,
                                               const unsigned* __restrict__ aw2,
                                               const int* __restrict__ binbased,
                                               const int* __restrict__ srh,
                                               unsigned* __restrict__ bw0,
                                               unsigned* __restrict__ bw1,
                                               unsigned* __restrict__ bw2,
                                               float* __restrict__ degInv,
                                               int* __restrict__ based_bk) {
    __shared__ int cur[NPB];
    __shared__ int part[256];
    __shared__ int sSub[2];
    __shared__ unsigned stw0[SCAP2];
    __shared__ unsigned stw1[SCAP2];
    __shared__ unsigned stw2[SCAP2];
    int bs = blockIdx.x, t = threadIdx.x;
    int b = bs >> 3, h = bs & 7;
    int beg = binbased[b], end = binbased[b + 1];
    int j0 = 2 * t, j1 = 2 * t + 1;
    int tot0 = 0, tot1 = 0;
    const int* gbh = srh + (size_t)(b << 2) * 512;
#pragma unroll
    for (int hh = 0; hh < SPLIT; hh++) {
        tot0 += gbh[hh * 512 + j0];
        tot1 += gbh[hh * 512 + j1];
    }
    int tsum = tot0 + tot1;
    part[t] = tsum;
    __syncthreads();
    for (int off = 1; off < 256; off <<= 1) {
        int v = (t >= off) ? part[t - off] : 0;
        __syncthreads();
        part[t] += v;
        __syncthreads();
    }
    int excl = part[t] - tsum;
    int gcur0 = beg + excl;
    int gcur1 = gcur0 + tot0;
    int lo = h << 6, hi = lo + NPB;
    if (j0 == lo) sSub[0] = gcur0;
    if (h < 7) { if (j0 == hi) sSub[1] = gcur0; }
    else if (t == 0) sSub[1] = end;
    if (h == 0) {
        int node0 = b << 9;
        if (node0 + j0 < N_NODES) degInv[node0 + j0] = 1.0f / fmaxf((float)tot0, 1.0f);
        if (node0 + j1 < N_NODES) degInv[node0 + j1] = 1.0f / fmaxf((float)tot1, 1.0f);
        if ((j0 & 63) == 0) {
            int k = j0 >> 6;
            int node = node0 + (k << 6);
            if (node < N_NODES) based_bk[(b << 3) + k] = beg + excl;
        }
        if (b == NBIN - 1 && t == 0) based_bk[NBK] = N_EDGES;
    }
    __syncthreads();
    int subbase = sSub[0];
    if (j0 >= lo && j0 < hi) cur[j0 - lo] = gcur0 - subbase;
    if (j1 >= lo && j1 < hi) cur[j1 - lo] = gcur1 - subbase;
    __syncthreads();
    for (int i = beg + t; i < end; i += 256) {
        unsigned r0 = aw0[i];
        int nib = (int)((r0 >> 17) & 511u);
        if ((nib >> 6) == h) {
            unsigned v1 = aw1[i];
            unsigned v2 = aw2[i];
            int p = atomicAdd(&cur[nib & 63], 1);
            unsigned w = (r0 & 0x1FFFFu) | ((unsigned)(nib & 63) << 17);
            if (p < SCAP2) { stw0[p] = w; stw1[p] = v1; stw2[p] = v2; }
            else { bw0[subbase + p] = w; bw1[subbase + p] = v1; bw2[subbase + p] = v2; }
        }
    }
    __syncthreads();
    int tot = sSub[1] - subbase;
    if (tot > SCAP2) tot = SCAP2;
    for (int i = t; i < tot; i += 256) {
        bw0[subbase + i] = stw0[i];
        bw1[subbase + i] = stw1[i];
        bw2[subbase + i] = stw2[i];
    }
}

// ==================== phase 5a: src-sort histogram ====================
__global__ __launch_bounds__(256) void ss_hist(const unsigned* __restrict__ sbufA,
                                               const int* __restrict__ binbases,
                                               int* __restrict__ ssh) {
    __shared__ int hist[512];
    int bs = blockIdx.x, t = threadIdx.x;
    int b = bs >> 2, h = bs & 3;
    hist[t] = 0; hist[t + 256] = 0;
    __syncthreads();
    int beg = binbases[b], end = binbases[b + 1];
    int len = end - beg;
    int p0 = beg + (int)((long long)len * h / SPLIT);
    int p1 = beg + (int)((long long)len * (h + 1) / SPLIT);
    for (int i = p0 + t; i < p1; i += 256)
        atomicAdd(&hist[(sbufA[i] >> 22) & 511u], 1);
    __syncthreads();
    int* g = ssh + (size_t)bs * 512;
    g[t] = hist[t];
    g[t + 256] = hist[t + 256];
}

// ==================== phase 5b: src-sort scatter — per-BUCKET sub-blocks, LDS staging ====================
__global__ __launch_bounds__(256) void ss_scat(const unsigned* __restrict__ sbufA,
                                               const int* __restrict__ binbases,
                                               const int* __restrict__ ssh,
                                               unsigned* __restrict__ sbufB,
                                               int* __restrict__ bases_bk) {
    __shared__ int cur[NPB];
    __shared__ int part[256];
    __shared__ int sSub[2];
    __shared__ unsigned stw[SCAP2];
    int bs = blockIdx.x, t = threadIdx.x;
    int b = bs >> 3, h = bs & 7;
    int beg = binbases[b], end = binbases[b + 1];
    int j0 = 2 * t, j1 = 2 * t + 1;
    int tot0 = 0, tot1 = 0;
    const int* gbh = ssh + (size_t)(b << 2) * 512;
#pragma unroll
    for (int hh = 0; hh < SPLIT; hh++) {
        tot0 += gbh[hh * 512 + j0];
        tot1 += gbh[hh * 512 + j1];
    }
    int tsum = tot0 + tot1;
    part[t] = tsum;
    __syncthreads();
    for (int off = 1; off < 256; off <<= 1) {
        int v = (t >= off) ? part[t - off] : 0;
        __syncthreads();
        part[t] += v;
        __syncthreads();
    }
    int excl = part[t] - tsum;
    int gcur0 = beg + excl;
    int gcur1 = gcur0 + tot0;
    int lo = h << 6, hi = lo + NPB;
    if (j0 == lo) sSub[0] = gcur0;
    if (h < 7) { if (j0 == hi) sSub[1] = gcur0; }
    else if (t == 0) sSub[1] = end;
    if (h == 0) {
        if ((j0 & 63) == 0) {
            int k = j0 >> 6;
            int node = (b << 9) + (k << 6);
            if (node < N_NODES) bases_bk[(b << 3) + k] = beg + excl;
        }
        if (b == NBIN - 1 && t == 0) bases_bk[NBK] = N_EDGES;
    }
    __syncthreads();
    int subbase = sSub[0];
    if (j0 >= lo && j0 < hi) cur[j0 - lo] = gcur0 - subbase;
    if (j1 >= lo && j1 < hi) cur[j1 - lo] = gcur1 - subbase;
    __syncthreads();
    for (int i = beg + t; i < end; i += 256) {
        unsigned w = sbufA[i];
        int nib = (int)((w >> 22) & 511u);
        if ((nib >> 6) == h) {
            int p = atomicAdd(&cur[nib & 63], 1);
            unsigned wc = (w & 0x3FFFFFu) | ((unsigned)(nib & 63) << 22);
            if (p < SCAP2) stw[p] = wc;
            else sbufB[subbase + p] = wc;
        }
    }
    __syncthreads();
    int tot = sSub[1] - subbase;
    if (tot > SCAP2) tot = SCAP2;
    for (int i = t; i < tot; i += 256)
        sbufB[subbase + i] = stw[i];
}

// ==================== layer-0 A/B tables (X = 0) ====================
__global__ __launch_bounds__(256) void ab_init(const float* __restrict__ x,
                                               const float* __restrict__ W1,
                                               const float* __restrict__ b1,
                                               unsigned* __restrict__ A,
                                               unsigned* __restrict__ B) {
    __shared__ float sW[8 * HID];
    __shared__ float sb[HID];
    int t = threadIdx.x;
    for (int i = t; i < 8 * HID; i += 256) sW[i] = W1[12 * HID + i];
    if (t < HID) sb[t] = b1[t];
    __syncthreads();
    int i = blockIdx.x * 256 + t;
    if (i >= N_NODES) return;
    float4 xv = reinterpret_cast<const float4*>(x)[i];
    float xf[4] = {xv.x, xv.y, xv.z, xv.w};
    float a[HID], bb[HID];
#pragma unroll
    for (int j = 0; j < HID; j++) { a[j] = sb[j]; bb[j] = 0.0f; }
#pragma unroll
    for (int r = 0; r < 4; r++) {
        float v = xf[r];
#pragma unroll
        for (int j = 0; j < HID; j++) {
            a[j]  = fmaf(v, sW[r * HID + j], a[j]);
            bb[j] = fmaf(v, sW[(4 + r) * HID + j], bb[j]);
        }
    }
    uint4* Ao = reinterpret_cast<uint4*>(A + (size_t)i * 8);
    Ao[0] = make_uint4(f2bf(a[0], a[1]), f2bf(a[2], a[3]), f2bf(a[4], a[5]), f2bf(a[6], a[7]));
    Ao[1] = make_uint4(f2bf(a[8], a[9]), f2bf(a[10], a[11]), f2bf(a[12], a[13]), f2bf(a[14], a[15]));
    uint4* Bo = reinterpret_cast<uint4*>(B + (size_t)i * 8);
    Bo[0] = make_uint4(f2bf(bb[0], bb[1]), f2bf(bb[2], bb[3]), f2bf(bb[4], bb[5]), f2bf(bb[6], bb[7]));
    Bo[1] = make_uint4(f2bf(bb[8], bb[9]), f2bf(bb[10], bb[11]), f2bf(bb[12], bb[13]), f2bf(bb[14], bb[15]));
}

// ==================== node projection: X,x -> next-layer A/B tables ====================
__global__ __launch_bounds__(256) void node_proj(const float* __restrict__ X,
                                                 const float* __restrict__ x,
                                                 const float* __restrict__ W1n,
                                                 const float* __restrict__ b1n,
                                                 unsigned* __restrict__ A,
                                                 unsigned* __restrict__ B) {
    __shared__ float sW[20 * HID];
    __shared__ float sb[HID];
    int t = threadIdx.x;
    for (int i = t; i < 20 * HID; i += 256) sW[i] = W1n[i];
    if (t < HID) sb[t] = b1n[t];
    __syncthreads();
    int i = blockIdx.x * 256 + t;
    if (i >= N_NODES) return;
    const float4* Xp = reinterpret_cast<const float4*>(X + (size_t)i * 8);
    float4 x0 = Xp[0], x1 = Xp[1];
    float Xv[LD] = {x0.x, x0.y, x0.z, x0.w, x1.x, x1.y};
    float4 xv = reinterpret_cast<const float4*>(x)[i];
    float xf[4] = {xv.x, xv.y, xv.z, xv.w};
    float a[HID], bb[HID];
#pragma unroll
    for (int j = 0; j < HID; j++) { a[j] = sb[j]; bb[j] = 0.0f; }
#pragma unroll
    for (int rr = 0; rr < LD; rr++) {
        float v = Xv[rr];
#pragma unroll
        for (int j = 0; j < HID; j++) {
            a[j]  = fmaf(v, sW[rr * HID + j], a[j]);
            bb[j] = fmaf(v, sW[(LD + rr) * HID + j], bb[j]);
        }
    }
#pragma unroll
    for (int rr = 0; rr < 4; rr++) {
        float v = xf[rr];
#pragma unroll
        for (int j = 0; j < HID; j++) {
            a[j]  = fmaf(v, sW[(12 + rr) * HID + j], a[j]);
            bb[j] = fmaf(v, sW[(16 + rr) * HID + j], bb[j]);
        }
    }
    uint4* Ao = reinterpret_cast<uint4*>(A + (size_t)i * 8);
    Ao[0] = make_uint4(f2bf(a[0], a[1]), f2bf(a[2], a[3]), f2bf(a[4], a[5]), f2bf(a[6], a[7]));
    Ao[1] = make_uint4(f2bf(a[8], a[9]), f2bf(a[10], a[11]), f2bf(a[12], a[13]), f2bf(a[14], a[15]));
    uint4* Bo = reinterpret_cast<uint4*>(B + (size_t)i * 8);
    Bo[0] = make_uint4(f2bf(bb[0], bb[1]), f2bf(bb[2], bb[3]), f2bf(bb[4], bb[5]), f2bf(bb[6], bb[7]));
    Bo[1] = make_uint4(f2bf(bb[8], bb[9]), f2bf(bb[10], bb[11]), f2bf(bb[12], bb[13]), f2bf(bb[14], bb[15]));
}

// ==================== per-layer edge kernel: lean, 2 edges/thread, hoisted A prefetch ====================
template <int LAST>
__global__ __launch_bounds__(512) void edge_layer(const unsigned* __restrict__ bw0,
                                                  const unsigned* __restrict__ bw1,
                                                  const unsigned* __restrict__ bw2,
                                                  const unsigned* __restrict__ Ain,
                                                  const unsigned* __restrict__ Bin,
                                                  const float* __restrict__ x,
                                                  const float* __restrict__ degInv,
                                                  const float* __restrict__ W1l,
                                                  const float* __restrict__ W2l,
                                                  const float* __restrict__ b2l,
                                                  const float* __restrict__ Wf,
                                                  const float* __restrict__ bfp,
                                                  const int* __restrict__ based_bk,
                                                  float* __restrict__ Xout,
                                                  float* __restrict__ Pout,
                                                  float* __restrict__ Pbuf) {
    __shared__ float sWea[4 * HID];
    __shared__ float sW2[HID * LD];
    __shared__ float sb2[LD];
    __shared__ float sWf[LD];
    __shared__ float sbf;
    __shared__ float accf[NPB * 8];     // [key*8 + o]
    __shared__ unsigned sB[NPB * 8];
    int t = threadIdx.x;
    int b = blockIdx.x;
    for (int i = t; i < 4 * HID; i += 512) sWea[i] = W1l[20 * HID + i];
    for (int i = t; i < HID * LD; i += 512) sW2[i] = W2l[i];
    if (t < LD) sb2[t] = b2l[t];
    if (LAST) {
        if (t < LD) sWf[t] = Wf[t];
        if (t == 0) sbf = bfp[0];
    }
    if (t < NPB * 8) accf[t] = 0.0f;
    {
        size_t base8 = (size_t)(b << 6) * 8;
        for (int i = t; i < NPB * 8; i += 512) {
            size_t gi = base8 + i;
            sB[i] = (gi < (size_t)N_NODES * 8) ? Bin[gi] : 0u;
        }
    }
    __syncthreads();

    int beg = based_bk[b], end = based_bk[b + 1];
    int abeg = beg & ~1;
    int nPairs = (end - abeg + 1) >> 1;
    int lane = t & 63;

    float out[LD];
    auto edge_compute = [&](uint4 ax, uint4 ay, unsigned w1w, unsigned w2w, int key) {
        const uint4* Bp = reinterpret_cast<const uint4*>(sB) + (key << 1);
        uint4 bx = Bp[0], by = Bp[1];
        float h[HID];
        h[0]  = bflo(ax.x) + bflo(bx.x);  h[1]  = bfhi(ax.x) + bfhi(bx.x);
        h[2]  = bflo(ax.y) + bflo(bx.y);  h[3]  = bfhi(ax.y) + bfhi(bx.y);
        h[4]  = bflo(ax.z) + bflo(bx.z);  h[5]  = bfhi(ax.z) + bfhi(bx.z);
        h[6]  = bflo(ax.w) + bflo(bx.w);  h[7]  = bfhi(ax.w) + bfhi(bx.w);
        h[8]  = bflo(ay.x) + bflo(by.x);  h[9]  = bfhi(ay.x) + bfhi(by.x);
        h[10] = bflo(ay.y) + bflo(by.y);  h[11] = bfhi(ay.y) + bfhi(by.y);
        h[12] = bflo(ay.z) + bflo(by.z);  h[13] = bfhi(ay.z) + bfhi(by.z);
        h[14] = bflo(ay.w) + bflo(by.w);  h[15] = bfhi(ay.w) + bfhi(by.w);
        float ef[4] = {bflo(w1w), bfhi(w1w), bflo(w2w), bfhi(w2w)};
#pragma unroll
        for (int rr = 0; rr < 4; rr++) {
            float v = ef[rr];
#pragma unroll
            for (int j = 0; j < HID; j++) h[j] = fmaf(v, sWea[rr * HID + j], h[j]);
        }
#pragma unroll
        for (int j = 0; j < HID; j++) h[j] = fmaxf(h[j], 0.0f);
        float mo[LD];
#pragma unroll
        for (int o = 0; o < LD; o++) mo[o] = sb2[o];
#pragma unroll
        for (int j = 0; j < HID; j++) {
            float hj = h[j];
#pragma unroll
            for (int o = 0; o < LD; o++) mo[o] = fmaf(hj, sW2[j * LD + o], mo[o]);
        }
#pragma unroll
        for (int o = 0; o < LD; o++) out[o] += mo[o];
    };

    for (int pb = 0; pb < nPairs; pb += 512) {
        int c = pb + t;
        int key = -1;
#pragma unroll
        for (int o = 0; o < LD; o++) out[o] = 0.0f;

        if (c < nPairs) {
            int p0 = abeg + (c << 1);
            uint2 r0 = *reinterpret_cast<const uint2*>(bw0 + p0);
            uint2 w1 = *reinterpret_cast<const uint2*>(bw1 + p0);
            uint2 w2 = *reinterpret_cast<const uint2*>(bw2 + p0);
            bool v0 = (p0 >= beg && p0 < end);
            bool v1 = (p0 + 1 < end);
            // hoisted A prefetch for BOTH edges (independent loads, issued before any compute)
            uint4 ax0, ay0, ax1, ay1;
            if (v0) {
                const uint4* Ap = reinterpret_cast<const uint4*>(Ain + (size_t)(r0.x & 0x1FFFFu) * 8);
                ax0 = Ap[0];
                ay0 = Ap[1];
            }
            if (v1) {
                const uint4* Ap = reinterpret_cast<const uint4*>(Ain + (size_t)(r0.y & 0x1FFFFu) * 8);
                ax1 = Ap[0];
                ay1 = Ap[1];
            }
            if (v0) {
                key = (int)((r0.x >> 17) & 63u);
                edge_compute(ax0, ay0, w1.x, w2.x, key);
            }
            if (v1) {
                int k1 = (int)((r0.y >> 17) & 63u);
                if (k1 != key) {
                    if (key >= 0) {
#pragma unroll
                        for (int o = 0; o < LD; o++) atomicAdd(&accf[(key << 3) + o], out[o]);
#pragma unroll
                        for (int o = 0; o < LD; o++) out[o] = 0.0f;
                    }
                    key = k1;
                }
                edge_compute(ax1, ay1, w1.y, w2.y, key);
            }
        }

        // wave segmented inclusive sum over per-thread partials (keys sorted)
#pragma unroll
        for (int st = 1; st < 64; st <<= 1) {
            int kup = __shfl_up(key, st, 64);
            bool same = (lane >= st) && (kup == key);
#pragma unroll
            for (int o = 0; o < LD; o++) {
                float v = __shfl_up(out[o], st, 64);
                if (same) out[o] += v;
            }
        }
        int knx = __shfl_down(key, 1, 64);
        bool tail = (lane == 63) || (knx != key);
        if (tail && key >= 0) {
#pragma unroll
            for (int o = 0; o < LD; o++) atomicAdd(&accf[(key << 3) + o], out[o]);
        }
    }
    __syncthreads();

    if (t < NPB) {
        int gid = (b << 6) + t;
        if (gid < N_NODES) {
            float inv = degInv[gid];
            float Xv[LD];
#pragma unroll
            for (int o = 0; o < LD; o++) Xv[o] = fmaxf(accf[(t << 3) + o] * inv, 0.0f);
            if (LAST) {
                float a2 = sbf;
#pragma unroll
                for (int o = 0; o < LD; o++) a2 = fmaf(Xv[o], sWf[o], a2);
                float P = fmaxf(a2, 0.0f);
                Pout[gid] = P;
                float fx = x[gid * F_NODE + 3];
                Pbuf[gid] = (fx != 0.0f) ? fx : P;
            } else {
                float4* Xp = reinterpret_cast<float4*>(Xout + (size_t)gid * 8);
                Xp[0] = make_float4(Xv[0], Xv[1], Xv[2], Xv[3]);
                Xp[1] = make_float4(Xv[4], Xv[5], 0.0f, 0.0f);
            }
        }
    }
}

// ==================== flows (original order, exact fp32) ====================
__global__ __launch_bounds__(256) void flows_noatomic(const int* __restrict__ ei,
                                                      const float* __restrict__ ea,
                                                      const float* __restrict__ Pbuf,
                                                      float* __restrict__ flows_out) {
    int e = blockIdx.x * 256 + threadIdx.x;
    if (e >= N_EDGES) return;
    int s = ei[e];
    int d = ei[N_EDGES + e];
    float ps = Pbuf[s], pd = Pbuf[d];
    float dp2 = ps * ps - pd * pd;
    float k = ea[(size_t)e * F_EDGE];
    float sg = (dp2 > 0.0f) ? 1.0f : ((dp2 < 0.0f) ? -1.0f : 0.0f);
    flows_out[e] = sg * sqrtf(fabsf(dp2) / k + EPSF);
}

// ==================== balance in-flow: recompute flows from sorted planes, segscan ====================
__global__ __launch_bounds__(256) void balance_in(const unsigned* __restrict__ bw0,
                                                  const unsigned* __restrict__ bw1,
                                                  const float* __restrict__ Pbuf,
                                                  const float* __restrict__ x,
                                                  const int* __restrict__ based_bk,
                                                  float* __restrict__ bal) {
    __shared__ float acc[NPB];
    __shared__ float pdl[NPB];
    int t = threadIdx.x;
    int b = blockIdx.x;
    if (t < NPB) {
        acc[t] = 0.0f;
        int gid = (b << 6) + t;
        pdl[t] = (gid < N_NODES) ? Pbuf[gid] : 0.0f;
    }
    __syncthreads();
    int beg = based_bk[b], end = based_bk[b + 1];
    int lane = t & 63;
    for (int base = beg; base < end; base += 256) {
        int p = base + t;
        bool valid = p < end;
        int key = -1;
        float f = 0.0f;
        if (valid) {
            unsigned r0 = bw0[p];
            int s = (int)(r0 & 0x1FFFFu);
            key = (int)((r0 >> 17) & 63u);
            float ps = Pbuf[s];
            float pd = pdl[key];
            float k = bflo(bw1[p]);
            float dp2 = ps * ps - pd * pd;
            float sg = (dp2 > 0.0f) ? 1.0f : ((dp2 < 0.0f) ? -1.0f : 0.0f);
            f = sg * sqrtf(fabsf(dp2) / k + EPSF);
        }
#pragma unroll
        for (int st = 1; st < 64; st <<= 1) {
            int kup = __shfl_up(key, st, 64);
            float v = __shfl_up(f, st, 64);
            if ((lane >= st) && (kup == key)) f += v;
        }
        int knx = __shfl_down(key, 1, 64);
        bool tail = (lane == 63) || (knx != key);
        if (valid && tail) atomicAdd(&acc[key], f);
    }
    __syncthreads();
    if (t < NPB) {
        int gid = (b << 6) + t;
        if (gid < N_NODES) bal[gid] = acc[t] + x[gid * F_NODE + 0];
    }
}

// ==================== balance out-flow (segscan over sorted sbufB) + imbalance ====================
__global__ __launch_bounds__(256) void balance_out(const unsigned* __restrict__ sbufB,
                                                   const float* __restrict__ flows,
                                                   const int* __restrict__ bases_bk,
                                                   const float* __restrict__ bal,
                                                   float* __restrict__ imb2) {
    __shared__ float acc[NPB];
    int t = threadIdx.x;
    if (t < NPB) acc[t] = 0.0f;
    __syncthreads();
    int b = blockIdx.x;
    int beg = bases_bk[b], end = bases_bk[b + 1];
    int lane = t & 63;
    for (int base = beg; base < end; base += 256) {
        int q = base + t;
        bool valid = q < end;
        int key = -1;
        float f = 0.0f;
        if (valid) {
            unsigned u = sbufB[q];
            key = (int)((u >> 22) & 63u);
            f = flows[u & 0x3FFFFFu];
        }
#pragma unroll
        for (int st = 1; st < 64; st <<= 1) {
            int kup = __shfl_up(key, st, 64);
            float v = __shfl_up(f, st, 64);
            if ((lane >= st) && (kup == key)) f += v;
        }
        int knx = __shfl_down(key, 1, 64);
        bool tail = (lane == 63) || (knx != key);
        if (valid && tail) atomicAdd(&acc[key], f);
    }
    __syncthreads();
    if (t < NPB) {
        float v = 0.0f;
        int gid = (b << 6) + t;
        if (gid < N_NODES) {
            float bv = bal[gid] - acc[t];
            v = bv * bv;
        }
#pragma unroll
        for (int off = 32; off > 0; off >>= 1) v += __shfl_down(v, off, 64);
        if (t == 0) atomicAdd(imb2, v);
    }
}

__global__ void fin_kernel(const float* __restrict__ imb2, float* __restrict__ out) {
    out[0] = sqrtf(imb2[0]);
}

// ==================== launch ====================
extern "C" void kernel_launch(void* const* d_in, const int* in_sizes, int n_in,
                              void* d_out, int out_size, void* d_ws, size_t ws_size,
                              hipStream_t stream) {
    const float* x   = (const float*)d_in[0];
    const float* ea  = (const float*)d_in[1];
    const int*   ei  = (const int*)d_in[2];
    const float* W1  = (const float*)d_in[3];
    const float* b1  = (const float*)d_in[4];
    const float* W2  = (const float*)d_in[5];
    const float* b2  = (const float*)d_in[6];
    const float* Wf  = (const float*)d_in[7];
    const float* bf_ = (const float*)d_in[8];
    float* out = (float*)d_out;

    const size_t N = N_NODES, E = N_EDGES;

    // ---- workspace layout (4B elements), ~110 MB ----
    size_t o = 0;
    auto alloc = [&](size_t n) { size_t r = o; o += (n + 3) & ~(size_t)3; return r; };
    size_t o_bw0      = alloc(E);
    size_t o_bw1      = alloc(E);
    size_t o_bw2      = alloc(E);
    size_t o_aw0      = alloc(E);      // sbufB overlays aw0 after sr_scat
    size_t o_aw1      = alloc(E);
    size_t o_aw2      = alloc(E);
    size_t o_sbufA    = alloc(E);
    size_t o_ghd      = alloc((size_t)NBIN * G1);
    size_t o_ghs      = alloc((size_t)NBIN * G1);
    size_t o_srh      = alloc((size_t)NSB * 512);
    size_t o_ssh      = alloc((size_t)NSB * 512);
    size_t o_totd     = alloc(NBIN);
    size_t o_tots     = alloc(NBIN);
    size_t o_binbased = alloc(NBIN + 1);
    size_t o_binbases = alloc(NBIN + 1);
    size_t o_basedbk  = alloc(NBK + 1);
    size_t o_basesbk  = alloc(NBK + 1);
    size_t o_degInv   = alloc(N);
    size_t o_A0       = alloc(8 * N);
    size_t o_B0       = alloc(8 * N);
    size_t o_A1       = alloc(8 * N);
    size_t o_B1       = alloc(8 * N);
    size_t o_X        = alloc(8 * N);
    size_t o_Pbuf     = alloc(N);
    size_t o_bal      = alloc(N);
    size_t o_imb2     = alloc(16);
    (void)o;

    int* wsi = (int*)d_ws;
    unsigned* bw0      = (unsigned*)(wsi + o_bw0);
    unsigned* bw1      = (unsigned*)(wsi + o_bw1);
    unsigned* bw2      = (unsigned*)(wsi + o_bw2);
    unsigned* aw0      = (unsigned*)(wsi + o_aw0);
    unsigned* aw1      = (unsigned*)(wsi + o_aw1);
    unsigned* aw2      = (unsigned*)(wsi + o_aw2);
    unsigned* sbufA    = (unsigned*)(wsi + o_sbufA);
    unsigned* sbufB    = (unsigned*)(wsi + o_aw0);   // overlay (aw* dead after sr_scat)
    int*      ghd      = wsi + o_ghd;
    int*      ghs      = wsi + o_ghs;
    int*      srh      = wsi + o_srh;
    int*      ssh      = wsi + o_ssh;
    int*      totd     = wsi + o_totd;
    int*      tots     = wsi + o_tots;
    int*      binbased = wsi + o_binbased;
    int*      binbases = wsi + o_binbases;
    int*      based_bk = wsi + o_basedbk;
    int*      bases_bk = wsi + o_basesbk;
    float*    degInv   = (float*)(wsi + o_degInv);
    unsigned* A0       = (unsigned*)(wsi + o_A0);
    unsigned* B0       = (unsigned*)(wsi + o_B0);
    unsigned* A1       = (unsigned*)(wsi + o_A1);
    unsigned* B1       = (unsigned*)(wsi + o_B1);
    float*    Xbuf     = (float*)(wsi + o_X);
    float*    Pbuf     = (float*)(wsi + o_Pbuf);
    float*    bal      = (float*)(wsi + o_bal);
    float*    imb2     = (float*)(wsi + o_imb2);

    const int NB = (N_NODES + 255) / 256;   // 391
    const int EB = (N_EDGES + 255) / 256;   // 12500

    hipMemsetAsync(imb2, 0, sizeof(float), stream);

    hist_kernel<<<G1, 256, 0, stream>>>(ei, ghd, ghs);
    scanb_kernel<<<NBIN, 256, 0, stream>>>(ghd, ghs, totd, tots);
    totscan_kernel<<<1, 256, 0, stream>>>(totd, tots, binbased, binbases);
    scatterA_kernel<<<G1, 256, 0, stream>>>(ei, ea, ghd, ghs, binbased, binbases,
                                            aw0, aw1, aw2, sbufA);
    sr_hist<<<NSB, 256, 0, stream>>>(aw0, binbased, srh);
    sr_scat<<<NSW, 256, 0, stream>>>(aw0, aw1, aw2, binbased, srh,
                                     bw0, bw1, bw2, degInv, based_bk);
    ss_hist<<<NSB, 256, 0, stream>>>(sbufA, binbases, ssh);
    ss_scat<<<NSW, 256, 0, stream>>>(sbufA, binbases, ssh, sbufB, bases_bk);

    ab_init<<<NB, 256, 0, stream>>>(x, W1, b1, A0, B0);

    for (int l = 0; l < NLAYER; l++) {
        const unsigned* Ain = (l & 1) ? A1 : A0;
        const unsigned* Bin = (l & 1) ? B1 : B0;
        unsigned* Aout = (l & 1) ? A0 : A1;
        unsigned* Bout = (l & 1) ? B0 : B1;
        const float* W1l = W1 + (size_t)l * 24 * HID;
        const float* W2l = W2 + (size_t)l * HID * LD;
        const float* b2l = b2 + (size_t)l * LD;
        if (l < NLAYER - 1) {
            edge_layer<0><<<NBK, 512, 0, stream>>>(bw0, bw1, bw2, Ain, Bin, x, degInv,
                                                   W1l, W2l, b2l, Wf, bf_, based_bk,
                                                   Xbuf, out, Pbuf);
            node_proj<<<NB, 256, 0, stream>>>(Xbuf, x,
                                              W1 + (size_t)(l + 1) * 24 * HID,
                                              b1 + (size_t)(l + 1) * HID,
                                              Aout, Bout);
        } else {
            edge_layer<1><<<NBK, 512, 0, stream>>>(bw0, bw1, bw2, Ain, Bin, x, degInv,
                                                   W1l, W2l, b2l, Wf, bf_, based_bk,
                                                   Xbuf, out, Pbuf);
        }
    }

    flows_noatomic<<<EB, 256, 0, stream>>>(ei, ea, Pbuf, out + N);
    balance_in<<<NBK, 256, 0, stream>>>(bw0, bw1, Pbuf, x, based_bk, bal);
    balance_out<<<NBK, 256, 0, stream>>>(sbufB, out + N, bases_bk, bal, imb2);
    fin_kernel<<<1, 1, 0, stream>>>(imb2, out + (size_t)N + E);
}